// Round 1
// baseline (438.340 us; speedup 1.0000x reference)
//
#include <hip/hip_runtime.h>
#include <hip/hip_bf16.h>

// Problem constants (from reference setup_inputs):
//   x: [B=64, C=2048, J=8]  fp32
//   W: [K=32, C=2048, I=16, J=8] fp32
//   out v: [B=64, K=32, I=16] fp32
#define Bn 64
#define Cn 2048
#define Jn 8
#define Kn 32
#define In 16
#define EPSf 1e-7f

// ---------------------------------------------------------------------------
// K1: S1[b,k,i] = sum_c sum_j W[k,c,i,j]*x[b,c,j];  v1 = squash(S1/32)
// grid: 2048 blocks (consecutive blocks: same k, different b -> W L2 reuse)
// block: 256 threads = 16 c_sub x 16 i
// ---------------------------------------------------------------------------
__global__ __launch_bounds__(256) void k1_pred_squash(
    const float* __restrict__ x, const float* __restrict__ W,
    float* __restrict__ v1)
{
    const int b = blockIdx.x & 63;
    const int k = blockIdx.x >> 6;
    const int tid  = threadIdx.x;
    const int csub = tid >> 4;   // 0..15
    const int i    = tid & 15;   // 0..15

    const float* __restrict__ Wk = W + (size_t)k * Cn * (In * Jn);
    const float* __restrict__ xb = x + (size_t)b * Cn * Jn;

    float acc = 0.0f;
    for (int c = csub; c < Cn; c += 16) {
        const float4* wp = reinterpret_cast<const float4*>(Wk + (size_t)c * 128 + i * 8);
        const float4* xp = reinterpret_cast<const float4*>(xb + (size_t)c * 8);
        float4 w0 = wp[0], w1 = wp[1];
        float4 x0 = xp[0], x1 = xp[1];
        acc += w0.x * x0.x + w0.y * x0.y + w0.z * x0.z + w0.w * x0.w
             + w1.x * x1.x + w1.y * x1.y + w1.z * x1.z + w1.w * x1.w;
    }

    __shared__ float red[16][17];
    red[csub][i] = acc;
    __syncthreads();
    for (int s = 8; s > 0; s >>= 1) {
        if (csub < s) red[csub][i] += red[csub + s][i];
        __syncthreads();
    }

    if (tid < 16) {
        float si = red[0][tid] * (1.0f / 32.0f);   // cc = 1/32 uniform in iter 1
        float sq = si * si;
        sq += __shfl_xor(sq, 1);
        sq += __shfl_xor(sq, 2);
        sq += __shfl_xor(sq, 4);
        sq += __shfl_xor(sq, 8);
        float f = (sq / (1.0f + sq)) * rsqrtf(sq + EPSf);
        v1[((size_t)b * Kn + k) * In + tid] = si * f;
    }
}

// ---------------------------------------------------------------------------
// K3: iter 2.  For each (b,c): u[k,i] recomputed, agr_k = <u[k,:],v1[b,k,:]>,
// cc = softmax_k(agr), s2[b,k,i] += cc_k * u[k,i].
// grid: 64 b x 16 chunks (128 c each) = 1024 blocks; consecutive blocks share
// the W chunk (different b) for L2 locality.
// block: 256 threads = 8 c_sub x 32 k. Softmax over k = 32-lane butterfly.
// ---------------------------------------------------------------------------
#define CCHUNK 128
__global__ __launch_bounds__(256) void k3_route(
    const float* __restrict__ x, const float* __restrict__ W,
    const float* __restrict__ v1, float* __restrict__ s2)
{
    const int b     = blockIdx.x & 63;
    const int chunk = blockIdx.x >> 6;
    const int tid  = threadIdx.x;
    const int k    = tid & 31;   // lane%32 == k
    const int csub = tid >> 5;   // 0..7

    // v1[b,k,:] resident in registers for the whole block
    float v1r[16];
    {
        const float* vp = v1 + ((size_t)b * Kn + k) * In;
        #pragma unroll
        for (int i = 0; i < 16; ++i) v1r[i] = vp[i];
    }

    float acc[16];
    #pragma unroll
    for (int i = 0; i < 16; ++i) acc[i] = 0.0f;

    const float* __restrict__ xb = x + (size_t)b * Cn * Jn;

    for (int t = 0; t < CCHUNK / 8; ++t) {
        const int c = chunk * CCHUNK + t * 8 + csub;
        const float4* xp = reinterpret_cast<const float4*>(xb + (size_t)c * 8);
        float4 x0 = xp[0], x1 = xp[1];

        const float* wp = W + ((size_t)k * Cn + c) * 128;
        float u[16];
        #pragma unroll
        for (int i = 0; i < 16; ++i) {
            const float4* w4 = reinterpret_cast<const float4*>(wp + i * 8);
            float4 w0 = w4[0], w1 = w4[1];
            u[i] = w0.x * x0.x + w0.y * x0.y + w0.z * x0.z + w0.w * x0.w
                 + w1.x * x1.x + w1.y * x1.y + w1.z * x1.z + w1.w * x1.w;
        }

        float agr = 0.0f;
        #pragma unroll
        for (int i = 0; i < 16; ++i) agr += u[i] * v1r[i];

        // softmax over the 32-lane k-group (xor masks stay within 32)
        float m = agr;
        m = fmaxf(m, __shfl_xor(m, 1));
        m = fmaxf(m, __shfl_xor(m, 2));
        m = fmaxf(m, __shfl_xor(m, 4));
        m = fmaxf(m, __shfl_xor(m, 8));
        m = fmaxf(m, __shfl_xor(m, 16));
        float e = __expf(agr - m);
        float ssum = e;
        ssum += __shfl_xor(ssum, 1);
        ssum += __shfl_xor(ssum, 2);
        ssum += __shfl_xor(ssum, 4);
        ssum += __shfl_xor(ssum, 8);
        ssum += __shfl_xor(ssum, 16);
        float cc = e / ssum;

        #pragma unroll
        for (int i = 0; i < 16; ++i) acc[i] += cc * u[i];
    }

    // reduce the 8 c_sub partials: xor-32 within wave, then LDS across 4 waves
    #pragma unroll
    for (int i = 0; i < 16; ++i) acc[i] += __shfl_xor(acc[i], 32);

    __shared__ float red[4][32][16];   // 8 KB
    const int wave = tid >> 6;
    const int lane = tid & 63;
    if (lane < 32) {
        #pragma unroll
        for (int i = 0; i < 16; ++i) red[wave][lane][i] = acc[i];
    }
    __syncthreads();

    for (int p = tid; p < Kn * In; p += 256) {
        const int kk = p >> 4;
        const int ii = p & 15;
        float sum = red[0][kk][ii] + red[1][kk][ii] + red[2][kk][ii] + red[3][kk][ii];
        atomicAdd(&s2[((size_t)b * Kn + kk) * In + ii], sum);
    }
}

// ---------------------------------------------------------------------------
// K4: out = squash(s2), one thread per (b,k)
// ---------------------------------------------------------------------------
__global__ __launch_bounds__(256) void k4_squash(
    const float* __restrict__ s2, float* __restrict__ out)
{
    const int t = blockIdx.x * blockDim.x + threadIdx.x;
    if (t >= Bn * Kn) return;
    const float* sp = s2 + (size_t)t * In;
    float s[16];
    float sq = 0.0f;
    #pragma unroll
    for (int i = 0; i < 16; ++i) { s[i] = sp[i]; sq += s[i] * s[i]; }
    float f = (sq / (1.0f + sq)) * rsqrtf(sq + EPSf);
    float* op = out + (size_t)t * In;
    #pragma unroll
    for (int i = 0; i < 16; ++i) op[i] = s[i] * f;
}

extern "C" void kernel_launch(void* const* d_in, const int* in_sizes, int n_in,
                              void* d_out, int out_size, void* d_ws, size_t ws_size,
                              hipStream_t stream)
{
    const float* x = (const float*)d_in[0];   // [64,2048,8]
    const float* W = (const float*)d_in[1];   // [32,2048,16,8]
    float* out = (float*)d_out;               // [64,32,16] = 32768 floats

    float* v1 = (float*)d_ws;                         // 32768 floats
    float* s2 = (float*)d_ws + (size_t)Bn * Kn * In;  // 32768 floats

    // zero the atomic accumulator (ws is poisoned 0xAA before every call)
    hipMemsetAsync(s2, 0, (size_t)Bn * Kn * In * sizeof(float), stream);

    k1_pred_squash<<<Bn * Kn, 256, 0, stream>>>(x, W, v1);
    k3_route<<<Bn * (Cn / CCHUNK), 256, 0, stream>>>(x, W, v1, s2);
    k4_squash<<<(Bn * Kn + 255) / 256, 256, 0, stream>>>(s2, out);
}

// Round 2
// 197.804 us; speedup vs baseline: 2.2160x; 2.2160x over previous
//
#include <hip/hip_runtime.h>

// x: [B=64, C=2048, J=8] fp32 ; W: [K=32, C=2048, I=16, J=8] fp32
// out v: [B=64, K=32, I=16] fp32
#define Bn 64
#define Cn 2048
#define Jn 8
#define Kn 32
#define In 16
#define EPSf 1e-7f

// ---------------------------------------------------------------------------
// Kernel A: iter-1 accumulate  S1[b,k,i] += sum_c W[k,c,i,:].x[b,c,:]
// tid = k*8 + ih  (k=0..31, ih=0..7); thread owns i = 2*ih, 2*ih+1.
// Consecutive ih lanes read contiguous W (line-coalesced). Bsub=4 batches
// share each W load. grid = 16 bgroups x 64 cgroups (32 c each).
// ---------------------------------------------------------------------------
#define BSUB_A 4
#define CPB_A  32
__global__ __launch_bounds__(256) void kA(const float* __restrict__ x,
                                          const float* __restrict__ W,
                                          float* __restrict__ S1)
{
    const int bg = blockIdx.x & 15;
    const int cg = blockIdx.x >> 4;
    const int k  = threadIdx.x >> 3;
    const int ih = threadIdx.x & 7;

    float acc[BSUB_A][2] = {};
    const int c0 = cg * CPB_A;

    for (int cl = 0; cl < CPB_A; ++cl) {
        const int c = c0 + cl;
        const float4* wp = (const float4*)(W + ((size_t)(k * Cn + c)) * 128 + ih * 16);
        float4 w0 = wp[0], w1 = wp[1], w2 = wp[2], w3 = wp[3];
        #pragma unroll
        for (int b = 0; b < BSUB_A; ++b) {
            const float4* xp = (const float4*)(x + ((size_t)((bg * BSUB_A + b) * Cn + c)) * 8);
            float4 x0 = xp[0], x1 = xp[1];
            acc[b][0] += w0.x*x0.x + w0.y*x0.y + w0.z*x0.z + w0.w*x0.w
                       + w1.x*x1.x + w1.y*x1.y + w1.z*x1.z + w1.w*x1.w;
            acc[b][1] += w2.x*x0.x + w2.y*x0.y + w2.z*x0.z + w2.w*x0.w
                       + w3.x*x1.x + w3.y*x1.y + w3.z*x1.z + w3.w*x1.w;
        }
    }
    #pragma unroll
    for (int b = 0; b < BSUB_A; ++b) {
        #pragma unroll
        for (int ii = 0; ii < 2; ++ii)
            atomicAdd(&S1[((size_t)(bg * BSUB_A + b) * Kn + k) * In + 2 * ih + ii],
                      acc[b][ii]);
    }
}

// ---------------------------------------------------------------------------
// squash kernel: out[t,:] = squash(in[t,:]*scale), one thread per (b,k)
// ---------------------------------------------------------------------------
__global__ __launch_bounds__(256) void squash_k(const float* __restrict__ in,
                                                float* __restrict__ out,
                                                float scale, int n)
{
    const int t = blockIdx.x * blockDim.x + threadIdx.x;
    if (t >= n) return;
    const float* ip = in + (size_t)t * In;
    float s[In];
    float sq = 0.0f;
    #pragma unroll
    for (int i = 0; i < In; ++i) { s[i] = ip[i] * scale; sq += s[i] * s[i]; }
    const float f = (sq / (1.0f + sq)) * rsqrtf(sq + EPSf);
    float* op = out + (size_t)t * In;
    #pragma unroll
    for (int i = 0; i < In; ++i) op[i] = s[i] * f;
}

// ---------------------------------------------------------------------------
// Kernel C: iter-2 routing. tid = k*8 + ih; thread owns i = 2*ih, 2*ih+1.
// Per 16-c chunk: phase1 computes u (kept in regs) + exp(agreement) into LDS
// (3 shuffles, no per-c softmax chain); phase2 one batched denominator
// reduction; phase3 pure register math. Bsub=2 b per block share W loads.
// grid = 32 bgroups x 32 cgroups (4 chunks of 16 c each).
// ---------------------------------------------------------------------------
#define BSUB_C 2
#define CCC    16
#define NCHUNK 4
__global__ __launch_bounds__(256) void kC(const float* __restrict__ x,
                                          const float* __restrict__ W,
                                          const float* __restrict__ v1,
                                          float* __restrict__ s2)
{
    const int bg = blockIdx.x & 31;
    const int cg = blockIdx.x >> 5;
    const int k  = threadIdx.x >> 3;
    const int ih = threadIdx.x & 7;

    __shared__ float e_s[BSUB_C][CCC][33];   // k padded 32->33
    __shared__ float dinv[BSUB_C * CCC];

    float v1r[BSUB_C][2];
    #pragma unroll
    for (int b = 0; b < BSUB_C; ++b) {
        const float* vp = v1 + ((size_t)((bg * BSUB_C + b) * Kn + k)) * In + 2 * ih;
        v1r[b][0] = vp[0];
        v1r[b][1] = vp[1];
    }

    float acc[BSUB_C][2] = {};

    for (int ch = 0; ch < NCHUNK; ++ch) {
        const int c0 = (cg * NCHUNK + ch) * CCC;
        float u0[BSUB_C][CCC];
        float u1[BSUB_C][CCC];

        // ---- phase 1: u into regs, exp(agreement) into LDS ----
        #pragma unroll
        for (int cl = 0; cl < CCC; ++cl) {
            const int c = c0 + cl;
            const float4* wp = (const float4*)(W + ((size_t)(k * Cn + c)) * 128 + ih * 16);
            float4 w0 = wp[0], w1 = wp[1], w2 = wp[2], w3 = wp[3];
            #pragma unroll
            for (int b = 0; b < BSUB_C; ++b) {
                const float4* xp = (const float4*)(x + ((size_t)((bg * BSUB_C + b) * Cn + c)) * 8);
                float4 x0 = xp[0], x1 = xp[1];
                float a0 = w0.x*x0.x + w0.y*x0.y + w0.z*x0.z + w0.w*x0.w
                         + w1.x*x1.x + w1.y*x1.y + w1.z*x1.z + w1.w*x1.w;
                float a1 = w2.x*x0.x + w2.y*x0.y + w2.z*x0.z + w2.w*x0.w
                         + w3.x*x1.x + w3.y*x1.y + w3.z*x1.z + w3.w*x1.w;
                u0[b][cl] = a0;
                u1[b][cl] = a1;
                float part = a0 * v1r[b][0] + a1 * v1r[b][1];
                part += __shfl_xor(part, 1);
                part += __shfl_xor(part, 2);
                part += __shfl_xor(part, 4);
                if (ih == 0) e_s[b][cl][k] = __expf(part);
            }
        }
        __syncthreads();

        // ---- phase 2: batched softmax denominators (32 (b,c) pairs) ----
        {
            const int p = threadIdx.x >> 3;   // 0..31
            const int l = threadIdx.x & 7;
            const int pb = p >> 4, pc = p & 15;
            float ssum = e_s[pb][pc][4 * l + 0] + e_s[pb][pc][4 * l + 1]
                       + e_s[pb][pc][4 * l + 2] + e_s[pb][pc][4 * l + 3];
            ssum += __shfl_xor(ssum, 1);
            ssum += __shfl_xor(ssum, 2);
            ssum += __shfl_xor(ssum, 4);
            if (l == 0) dinv[p] = 1.0f / ssum;
        }
        __syncthreads();

        // ---- phase 3: weighted accumulate (pure register math) ----
        #pragma unroll
        for (int cl = 0; cl < CCC; ++cl) {
            #pragma unroll
            for (int b = 0; b < BSUB_C; ++b) {
                const float cc = e_s[b][cl][k] * dinv[b * CCC + cl];
                acc[b][0] += cc * u0[b][cl];
                acc[b][1] += cc * u1[b][cl];
            }
        }
        __syncthreads();   // protect e_s before next chunk overwrites
    }

    #pragma unroll
    for (int b = 0; b < BSUB_C; ++b) {
        #pragma unroll
        for (int ii = 0; ii < 2; ++ii)
            atomicAdd(&s2[((size_t)(bg * BSUB_C + b) * Kn + k) * In + 2 * ih + ii],
                      acc[b][ii]);
    }
}

extern "C" void kernel_launch(void* const* d_in, const int* in_sizes, int n_in,
                              void* d_out, int out_size, void* d_ws, size_t ws_size,
                              hipStream_t stream)
{
    const float* x = (const float*)d_in[0];   // [64,2048,8]
    const float* W = (const float*)d_in[1];   // [32,2048,16,8]
    float* out = (float*)d_out;               // [64,32,16]

    const size_t NV = (size_t)Bn * Kn * In;   // 32768
    float* S1 = (float*)d_ws;                 // accumulator iter 1
    float* s2 = (float*)d_ws + NV;            // accumulator iter 2
    float* v1 = (float*)d_ws + 2 * NV;        // squashed iter-1 output

    // zero both atomic accumulators (adjacent) in one memset
    hipMemsetAsync(S1, 0, 2 * NV * sizeof(float), stream);

    kA<<<16 * 64, 256, 0, stream>>>(x, W, S1);
    squash_k<<<(Bn * Kn + 255) / 256, 256, 0, stream>>>(S1, v1, 1.0f / 32.0f, Bn * Kn);
    kC<<<32 * 32, 256, 0, stream>>>(x, W, v1, s2);
    squash_k<<<(Bn * Kn + 255) / 256, 256, 0, stream>>>(s2, out, 1.0f, Bn * Kn);
}